// Round 3
// baseline (445.935 us; speedup 1.0000x reference)
//
#include <hip/hip_runtime.h>
#include <hip/hip_bf16.h>
#include <stdint.h>

// LinearDiscriminator: [T,B,H] fp32 -> MLP(1024->100->10->1) -> logsigmoid
// -> masked sum over T -> exp -> [B] fp32.  T=2048 B=32 H=1024.
// R3: M=128/block (512 blocks). W1 bf16 staged ONCE per block via
// global_load_lds (width=16) into a fragment-packed LDS layout (lane-linear,
// conflict-free), double-buffered BK=64 chunks, 1 barrier/chunk.
// Encoder A-fragments loaded per-lane from global, predicated on t<len[b].

#define T_DIM 2048
#define B_DIM 32
#define H_DIM 1024
#define L1_DIM 100
#define L2_DIM 10
#define K2_PAD 128
#define NPART 512              // blocks in mlp_main

#define W1B_ELEMS (112 * 1024)  // bf16 count
#define W2B_ELEMS (16 * 128)
#define PART_OFF_BYTES ((W1B_ELEMS + W2B_ELEMS) * 2)

#define CHUNK_BYTES 14336       // 112x64 bf16 fragment-packed
#define LDSH_OFF    0           // ldsH [128][136] bf16 unioned over both bufs
#define LDSW2_OFF   34816
#define LDSPART_OFF 39168
#define LDS_TOTAL   39680

typedef float v4f __attribute__((ext_vector_type(4)));
typedef short s8  __attribute__((ext_vector_type(8)));

static __device__ __forceinline__ unsigned short f2bf(float f) {
    unsigned int u = __float_as_uint(f);
    u += 0x7fffu + ((u >> 16) & 1u);
    return (unsigned short)(u >> 16);
}

static __device__ __forceinline__ s8 pack8(float4 a, float4 b) {
    union { s8 v; __hip_bfloat162 h[4]; } u;
    u.h[0] = __float22bfloat162_rn(make_float2(a.x, a.y));
    u.h[1] = __float22bfloat162_rn(make_float2(a.z, a.w));
    u.h[2] = __float22bfloat162_rn(make_float2(b.x, b.y));
    u.h[3] = __float22bfloat162_rn(make_float2(b.z, b.w));
    return u.v;
}

// ---------------- kernel 0: weight convert + pad ----------------
__global__ void convert_weights(const float* __restrict__ W1,
                                const float* __restrict__ W2,
                                unsigned short* __restrict__ wsb) {
    int i = blockIdx.x * 256 + threadIdx.x;
    if (i < W1B_ELEMS) {
        int row = i >> 10, col = i & 1023;
        float v = (row < L1_DIM) ? W1[row * H_DIM + col] : 0.0f;
        wsb[i] = f2bf(v);
    } else {
        int j = i - W1B_ELEMS;
        if (j < W2B_ELEMS) {
            int r = j >> 7, c = j & 127;
            float v = (r < L2_DIM && c < L1_DIM) ? W2[r * L1_DIM + c] : 0.0f;
            wsb[W1B_ELEMS + j] = f2bf(v);
        }
    }
}

// ---------------- kernel 1: main fused MLP ----------------
__global__ __launch_bounds__(256) void mlp_main(
    const float* __restrict__ enc,      // [T][B][H] fp32
    const int*   __restrict__ lenp,     // int32 or int64 (runtime-detected)
    const float* __restrict__ b1,
    const float* __restrict__ b2,
    const float* __restrict__ W3,
    const float* __restrict__ b3,
    const unsigned short* __restrict__ w1b,  // bf16 [112][1024]
    const unsigned short* __restrict__ w2b,  // bf16 [16][128]
    float* __restrict__ partials)            // fp32 [32][NPART]
{
    __shared__ __align__(16) unsigned char smem[LDS_TOTAL];

    const int tid  = threadIdx.x;
    const int blk  = blockIdx.x;
    const int lane = tid & 63;
    const int w    = tid >> 6;    // wave 0..3
    const int m    = lane & 15;
    const int q    = lane >> 4;

    const bool is64 = (lenp[1] == 0);  // int64 lengths>=1 => word1 of elem0 == 0

    int maxlen = 0;
    for (int i = 0; i < B_DIM; ++i) {
        int L = is64 ? lenp[2 * i] : lenp[i];
        maxlen = max(maxlen, L);
    }
    if (4 * blk >= maxlen) {
        if (tid < 32) partials[tid * NPART + blk] = 0.0f;
        return;
    }

    // this wave's t; frag rows: f=0 -> b=m, f=1 -> b=16+m
    const int t = 4 * blk + w;
    const int len0 = is64 ? lenp[2 * m] : lenp[m];
    const int len1 = is64 ? lenp[2 * (16 + m)] : lenp[16 + m];
    const bool pred0 = (t < len0);
    const bool pred1 = (t < len1);
    const bool waveActive = (t < maxlen);

    // stage W2 [16][128] bf16 -> LDS pitch 136 (one uint4/thread)
    {
        unsigned short* ldsW2 = (unsigned short*)(smem + LDSW2_OFF);
        int r = tid >> 4, c = (tid & 15) << 3;
        *(uint4*)(ldsW2 + r * 136 + c) = *(const uint4*)(w2b + r * K2_PAD + c);
    }

    // per-lane constants
    float b1v[7];
#pragma unroll
    for (int nt = 0; nt < 7; ++nt) {
        int n = nt * 16 + m;
        b1v[nt] = (n < L1_DIM) ? b1[n] : 0.0f;
    }
    const float b2v = (m < L2_DIM) ? b2[m] : 0.0f;
    const float w3v = (m < L2_DIM) ? W3[m] : 0.0f;
    const float b3s = b3[0];

    const float* ap0 = enc + (size_t)(blk * 128 + w * 32 + m) * H_DIM + q * 8;
    const float* ap1 = ap0 + 16 * H_DIM;
    const int fragoff = lane * 16;   // byte offset of this lane's 16B slot

    v4f acc0[7], acc1[7];
#pragma unroll
    for (int nt = 0; nt < 7; ++nt) { acc0[nt] = (v4f)0.0f; acc1[nt] = (v4f)0.0f; }

    // stage chunk kc into LDS at byte base BASE (fragment-packed, 896 x 16B)
#define STAGE(kc, BASE)                                                        \
    {                                                                          \
        _Pragma("unroll")                                                      \
        for (int it = 0; it < 4; ++it) {                                       \
            int j = it * 256 + tid;                                            \
            if (it < 3 || tid < 128) {                                         \
                int rest = j >> 6;            /* wave-uniform */               \
                int ks = (rest >= 7) ? 1 : 0;                                  \
                int nt = rest - ks * 7;                                        \
                const unsigned short* g = w1b + (nt * 16 + (j & 15)) * H_DIM + \
                                          (kc) * 64 + ks * 32 + ((j >> 4) & 3) * 8; \
                __builtin_amdgcn_global_load_lds(                              \
                    (const __attribute__((address_space(1))) unsigned int*)g,  \
                    (__attribute__((address_space(3))) unsigned int*)           \
                        (smem + (BASE) + (j & ~63) * 16),                      \
                    16, 0, 0);                                                 \
            }                                                                  \
        }                                                                      \
    }

#define KBODY(kc, RD, WR)                                                      \
    {                                                                          \
        if ((kc) < 15) STAGE((kc) + 1, WR);                                    \
        if (waveActive) {                                                      \
            const int kb = (kc) * 64;                                          \
            const float4 z4 = make_float4(0.f, 0.f, 0.f, 0.f);                 \
            float4 a00 = pred0 ? *(const float4*)(ap0 + kb)      : z4;         \
            float4 a01 = pred0 ? *(const float4*)(ap0 + kb + 4)  : z4;         \
            float4 a02 = pred0 ? *(const float4*)(ap0 + kb + 32) : z4;         \
            float4 a03 = pred0 ? *(const float4*)(ap0 + kb + 36) : z4;         \
            float4 a10 = pred1 ? *(const float4*)(ap1 + kb)      : z4;         \
            float4 a11 = pred1 ? *(const float4*)(ap1 + kb + 4)  : z4;         \
            float4 a12 = pred1 ? *(const float4*)(ap1 + kb + 32) : z4;         \
            float4 a13 = pred1 ? *(const float4*)(ap1 + kb + 36) : z4;         \
            s8 af0 = pack8(a00, a01);                                          \
            s8 af1 = pack8(a10, a11);                                          \
            _Pragma("unroll")                                                  \
            for (int nt = 0; nt < 7; ++nt) {                                   \
                s8 bf = *(const s8*)(smem + (RD) + nt * 1024 + fragoff);       \
                acc0[nt] = __builtin_amdgcn_mfma_f32_16x16x32_bf16(af0, bf, acc0[nt], 0, 0, 0); \
                acc1[nt] = __builtin_amdgcn_mfma_f32_16x16x32_bf16(af1, bf, acc1[nt], 0, 0, 0); \
            }                                                                  \
            af0 = pack8(a02, a03);                                             \
            af1 = pack8(a12, a13);                                             \
            _Pragma("unroll")                                                  \
            for (int nt = 0; nt < 7; ++nt) {                                   \
                s8 bf = *(const s8*)(smem + (RD) + (7 + nt) * 1024 + fragoff); \
                acc0[nt] = __builtin_amdgcn_mfma_f32_16x16x32_bf16(af0, bf, acc0[nt], 0, 0, 0); \
                acc1[nt] = __builtin_amdgcn_mfma_f32_16x16x32_bf16(af1, bf, acc1[nt], 0, 0, 0); \
            }                                                                  \
        }                                                                      \
        __syncthreads();                                                       \
    }

    STAGE(0, 0)
    __syncthreads();

    KBODY(0, 0, CHUNK_BYTES)
    KBODY(1, CHUNK_BYTES, 0)
    KBODY(2, 0, CHUNK_BYTES)
    KBODY(3, CHUNK_BYTES, 0)
    KBODY(4, 0, CHUNK_BYTES)
    KBODY(5, CHUNK_BYTES, 0)
    KBODY(6, 0, CHUNK_BYTES)
    KBODY(7, CHUNK_BYTES, 0)
    KBODY(8, 0, CHUNK_BYTES)
    KBODY(9, CHUNK_BYTES, 0)
    KBODY(10, 0, CHUNK_BYTES)
    KBODY(11, CHUNK_BYTES, 0)
    KBODY(12, 0, CHUNK_BYTES)
    KBODY(13, CHUNK_BYTES, 0)
    KBODY(14, 0, CHUNK_BYTES)
    KBODY(15, CHUNK_BYTES, 0)

#undef KBODY
#undef STAGE

    // ---- h1 = relu(acc + b1) -> ldsH [128][136] bf16 (aliases staging bufs) ----
    unsigned short* ldsH = (unsigned short*)(smem + LDSH_OFF);
#pragma unroll
    for (int f = 0; f < 2; ++f) {
#pragma unroll
        for (int nt = 0; nt < 7; ++nt) {
#pragma unroll
            for (int reg = 0; reg < 4; ++reg) {
                int row = w * 32 + f * 16 + q * 4 + reg;
                int col = nt * 16 + m;
                float a = f ? acc1[nt][reg] : acc0[nt][reg];
                ldsH[row * 136 + col] = f2bf(fmaxf(a + b1v[nt], 0.0f));
            }
        }
    }
    // zero K-pad cols 112..127 (128 rows x 16 cols, one uint4/thread)
    {
        int r = tid >> 1, c = 112 + (tid & 1) * 8;
        uint4 z; z.x = z.y = z.z = z.w = 0u;
        *(uint4*)(ldsH + r * 136 + c) = z;
    }
    __syncthreads();

    // ---- layer-2 MFMA: M=32/wave over K=128 ----
    unsigned short* ldsW2 = (unsigned short*)(smem + LDSW2_OFF);
    v4f acc2[2];
    acc2[0] = (v4f)0.0f; acc2[1] = (v4f)0.0f;
#pragma unroll
    for (int ks2 = 0; ks2 < 4; ++ks2) {
        s8 bw = *(const s8*)(ldsW2 + m * 136 + ks2 * 32 + q * 8);
#pragma unroll
        for (int f = 0; f < 2; ++f) {
            s8 ah = *(const s8*)(ldsH + (w * 32 + f * 16 + m) * 136 + ks2 * 32 + q * 8);
            acc2[f] = __builtin_amdgcn_mfma_f32_16x16x32_bf16(ah, bw, acc2[f], 0, 0, 0);
        }
    }

    // ---- layer 3 + logsigmoid + per-t mask ----
    float* ldsPart = (float*)(smem + LDSPART_OFF);   // [4][32]
#pragma unroll
    for (int f = 0; f < 2; ++f) {
        v4f zv;
#pragma unroll
        for (int reg = 0; reg < 4; ++reg)
            zv[reg] = fmaxf(acc2[f][reg] + b2v, 0.0f) * w3v;
#pragma unroll
        for (int msk = 1; msk < 16; msk <<= 1) {
#pragma unroll
            for (int reg = 0; reg < 4; ++reg)
                zv[reg] += __shfl_xor(zv[reg], msk, 16);
        }
        if (m == 0) {
#pragma unroll
            for (int reg = 0; reg < 4; ++reg) {
                int b = f * 16 + q * 4 + reg;
                int lenB = is64 ? lenp[2 * b] : lenp[b];
                float logit = zv[reg] + b3s;
                float logp  = fminf(logit, 0.0f) - log1pf(__expf(-fabsf(logit)));
                ldsPart[w * 32 + b] = (t < lenB) ? logp : 0.0f;
            }
        }
    }
    __syncthreads();
    if (tid < 32)
        partials[tid * NPART + blk] =
            (ldsPart[tid] + ldsPart[32 + tid]) + (ldsPart[64 + tid] + ldsPart[96 + tid]);
}

// ---------------- kernel 2: reduce + exp ----------------
__global__ void finalize(const float* __restrict__ partials,
                         float* __restrict__ out) {
    const int b = blockIdx.x;
    const int tid = threadIdx.x;
    float s = 0.0f;
    for (int i = tid; i < NPART; i += 256) s += partials[b * NPART + i];
#pragma unroll
    for (int off = 32; off > 0; off >>= 1) s += __shfl_down(s, off, 64);
    __shared__ float red[4];
    if ((tid & 63) == 0) red[tid >> 6] = s;
    __syncthreads();
    if (tid == 0) out[b] = expf(red[0] + red[1] + red[2] + red[3]);
}

extern "C" void kernel_launch(void* const* d_in, const int* in_sizes, int n_in,
                              void* d_out, int out_size, void* d_ws, size_t ws_size,
                              hipStream_t stream) {
    const float* enc = (const float*)d_in[0];
    const int*   len = (const int*)d_in[1];
    const float* W1  = (const float*)d_in[2];
    const float* b1  = (const float*)d_in[3];
    const float* W2  = (const float*)d_in[4];
    const float* b2  = (const float*)d_in[5];
    const float* W3  = (const float*)d_in[6];
    const float* b3  = (const float*)d_in[7];

    unsigned short* wsb = (unsigned short*)d_ws;
    float* partials = (float*)((char*)d_ws + PART_OFF_BYTES);
    float* out = (float*)d_out;

    convert_weights<<<(W1B_ELEMS + W2B_ELEMS + 255) / 256, 256, 0, stream>>>(W1, W2, wsb);
    mlp_main<<<NPART, 256, 0, stream>>>(enc, len, b1, b2, W3, b3,
                                        wsb, wsb + W1B_ELEMS, partials);
    finalize<<<B_DIM, 256, 0, stream>>>(partials, out);
}